// Round 1
// baseline (348.974 us; speedup 1.0000x reference)
//
#include <hip/hip_runtime.h>
#include <hip/hip_bf16.h>

#define Bc 8
#define Sc 2048
#define Hc 8
#define Dc 64

typedef __bf16 bf16x8 __attribute__((ext_vector_type(8)));
typedef float f32x4 __attribute__((ext_vector_type(4)));

// softmax scale: (1/sqrt(64)) * log2(e)
#define SCALE_LOG2E 0.18033688011112042f

__device__ __forceinline__ f32x4 mfma16(bf16x8 a, bf16x8 b, f32x4 c) {
  return __builtin_amdgcn_mfma_f32_16x16x32_bf16(a, b, c, 0, 0, 0);
}

__device__ __forceinline__ bf16x8 cvt8(const float* __restrict__ p) {
  bf16x8 r;
#pragma unroll
  for (int i = 0; i < 8; ++i) r[i] = (__bf16)p[i];
  return r;
}

__device__ __forceinline__ f32x4 zero4() {
  f32x4 z = {0.f, 0.f, 0.f, 0.f};
  return z;
}

typedef __attribute__((address_space(1))) void as1_void;
typedef __attribute__((address_space(3))) void as3_void;

// async global->LDS, 16B per lane; LDS dest is wave-uniform base + lane*16
__device__ __forceinline__ void lds_load16(const void* gsrc, void* ldst) {
  __builtin_amdgcn_global_load_lds((as1_void*)(void*)gsrc, (as3_void*)ldst, 16, 0, 0);
}

// ---------------------------------------------------------------------------
// Kernel 1: fused QKV projection.
//   q[b,h,s,e] = sum_d x[b,s,h,d] * Wq[e,d] + bq[e]   -> Qb [bh][s][e] bf16
//   k likewise                                        -> Kb [bh][s][e] bf16
//   v stored TRANSPOSED                               -> Vt [bh][e][s] bf16
// Flat row index r = b*S*H + s*H + h (all pow2: b=r>>14, s=(r>>3)&2047, h=r&7).
// Each wave does 16 rows per iter via 16x16x32 MFMA; 4 iters per block.
// ---------------------------------------------------------------------------
__global__ __launch_bounds__(256) void qkv_kernel(
    const float* __restrict__ x,
    const float* __restrict__ Wq, const float* __restrict__ bq,
    const float* __restrict__ Wk, const float* __restrict__ bk,
    const float* __restrict__ Wv, const float* __restrict__ bv,
    __bf16* __restrict__ Qb, __bf16* __restrict__ Kb, __bf16* __restrict__ Vt)
{
  const int tid = threadIdx.x;
  const int wid = tid >> 6;
  const int lane = tid & 63;
  const int lr = lane & 15;   // A/B fragment row selector
  const int lg = lane >> 4;   // k-group selector

  // Weight fragments: frag(W, cb, dc) = W[(cb*16+lr)][dc*32 + lg*8 .. +8]
  bf16x8 wqf[4][2], wkf[4][2], wvf[4][2];
#pragma unroll
  for (int cb = 0; cb < 4; ++cb)
#pragma unroll
    for (int dc = 0; dc < 2; ++dc) {
      const int off = (cb * 16 + lr) * Dc + dc * 32 + lg * 8;
      wqf[cb][dc] = cvt8(Wq + off);
      wkf[cb][dc] = cvt8(Wk + off);
      wvf[cb][dc] = cvt8(Wv + off);
    }
  float bqv[4], bkv[4], bvv2[4][4];
#pragma unroll
  for (int cb = 0; cb < 4; ++cb) {
    bqv[cb] = bq[cb * 16 + lr];
    bkv[cb] = bk[cb * 16 + lr];
  }
#pragma unroll
  for (int eb = 0; eb < 4; ++eb)
#pragma unroll
    for (int rr = 0; rr < 4; ++rr) bvv2[eb][rr] = bv[eb * 16 + lg * 4 + rr];

#pragma unroll 1
  for (int it = 0; it < 4; ++it) {
    const int r0 = blockIdx.x * 256 + it * 64 + wid * 16;
    // x fragment: serves as A (for q,k) and as B (for swapped v)
    bf16x8 xf[2];
#pragma unroll
    for (int dc = 0; dc < 2; ++dc)
      xf[dc] = cvt8(x + (size_t)(r0 + lr) * Dc + dc * 32 + lg * 8);

    // ---- Q and K (C-layout: row=q-row-in-tile=(lg*4+rr), col=e=cb*16+lr)
#pragma unroll
    for (int m = 0; m < 2; ++m) {
      __bf16* outp = m ? Kb : Qb;
#pragma unroll
      for (int cb = 0; cb < 4; ++cb) {
        f32x4 acc = zero4();
        acc = mfma16(xf[0], m ? wkf[cb][0] : wqf[cb][0], acc);
        acc = mfma16(xf[1], m ? wkf[cb][1] : wqf[cb][1], acc);
        const float bb = m ? bkv[cb] : bqv[cb];
#pragma unroll
        for (int rr = 0; rr < 4; ++rr) {
          const int r = r0 + lg * 4 + rr;
          const int b = r >> 14, s = (r >> 3) & (Sc - 1), h = r & 7;
          outp[((size_t)(b * Hc + h) * Sc + s) * Dc + cb * 16 + lr] =
              (__bf16)(acc[rr] + bb);
        }
      }
    }
    // ---- V swapped: Vt[e][row]; C-layout: row=e=(eb*16+lg*4+rr), col=x-row=lr
    {
      const int r = r0 + lr;
      const int b = r >> 14, s = (r >> 3) & (Sc - 1), h = r & 7;
      __bf16* vb = Vt + ((size_t)(b * Hc + h) * Dc) * Sc + s;
#pragma unroll
      for (int eb = 0; eb < 4; ++eb) {
        f32x4 acc = zero4();
        acc = mfma16(wvf[eb][0], xf[0], acc);
        acc = mfma16(wvf[eb][1], xf[1], acc);
#pragma unroll
        for (int rr = 0; rr < 4; ++rr) {
          const int e = eb * 16 + lg * 4 + rr;
          vb[(size_t)e * Sc] = (__bf16)(acc[rr] + bvv2[eb][rr]);
        }
      }
    }
  }
}

// ---------------------------------------------------------------------------
// Kernel 2: flash attention + fused output projection.
// Block = 256 thr (4 waves). QBLK=64 (16 q-rows/wave), KBLK=64, 32 k-tiles.
// K tile LDS [64][64] bf16, Vt tile LDS [64][64] bf16 ([d][k]) — both staged
// with global_load_lds(16B), XOR-swizzled source (slot ^= row&7) so that the
// ds_read_b128 fragment reads are bank-conflict-free.
// P/O re-layout buffer per wave: [16][72] bf16 (stride-72 pad => conflict-free).
// ---------------------------------------------------------------------------
__global__ __launch_bounds__(256) void attn_kernel(
    const __bf16* __restrict__ Qb, const __bf16* __restrict__ Kb,
    const __bf16* __restrict__ Vt, const float* __restrict__ Wo,
    const float* __restrict__ bo, float* __restrict__ out)
{
  __shared__ __align__(16) __bf16 kls[64 * 64];
  __shared__ __align__(16) __bf16 vls[64 * 64];
  __shared__ __align__(16) __bf16 pls[4][16 * 72];

  const int tid = threadIdx.x;
  const int wid = tid >> 6;
  const int lane = tid & 63;
  const int lr = lane & 15;
  const int lg = lane >> 4;

  // XCD-aware decode: all 32 q-blocks of one bh land on one XCD (L2 reuse)
  const int bid = blockIdx.x;
  const int bh = (bid & 7) * 8 + ((bid >> 3) & 7);
  const int qb = bid >> 6;
  const int b = bh >> 3, h = bh & 7;
  const int q0 = qb * 64;

  const __bf16* Kbase = Kb + (size_t)bh * Sc * Dc;
  const __bf16* Vbase = Vt + (size_t)bh * Dc * Sc;

  // Q fragments (A-operand): row = lr, k-chunk dc*32 + lg*8
  bf16x8 qf[2];
  {
    const __bf16* qp = Qb + ((size_t)bh * Sc + q0 + wid * 16 + lr) * Dc + lg * 8;
    qf[0] = *(const bf16x8*)(qp);
    qf[1] = *(const bf16x8*)(qp + 32);
  }

  f32x4 o[4];
#pragma unroll
  for (int db = 0; db < 4; ++db) o[db] = zero4();
  float mrow[4], lrow[4];
#pragma unroll
  for (int rr = 0; rr < 4; ++rr) { mrow[rr] = -1e30f; lrow[rr] = 0.f; }

#pragma unroll 1
  for (int kt = 0; kt < Sc / 64; ++kt) {
    const int k0 = kt * 64;
    // stage K: LDS slot s holds global 8-elem chunk ((s&7) ^ (row&7)) of row s>>3
#pragma unroll
    for (int i = 0; i < 2; ++i) {
      const int s = i * 256 + tid;
      const int r = s >> 3, c = s & 7;
      lds_load16(Kbase + (size_t)(k0 + r) * Dc + ((c ^ (r & 7)) * 8),
                 &kls[(i * 256 + wid * 64) * 8]);
    }
    // stage Vt rows (d-major), same swizzle along k-chunks
#pragma unroll
    for (int i = 0; i < 2; ++i) {
      const int s = i * 256 + tid;
      const int d = s >> 3, c = s & 7;
      lds_load16(Vbase + (size_t)d * Sc + k0 + ((c ^ (d & 7)) * 8),
                 &vls[(i * 256 + wid * 64) * 8]);
    }
    asm volatile("s_waitcnt vmcnt(0)" ::: "memory");
    __syncthreads();

    // ---- QK^T: e[kk] is 16q x 16k block kk; lane holds rows lg*4+rr, col lr
    f32x4 e[4];
#pragma unroll
    for (int kk = 0; kk < 4; ++kk) {
      e[kk] = zero4();
#pragma unroll
      for (int dc = 0; dc < 2; ++dc) {
        const int row = kk * 16 + lr;
        bf16x8 kf = *(const bf16x8*)(&kls[row * 64 + (((dc * 4 + lg) ^ (row & 7)) * 8)]);
        e[kk] = mfma16(qf[dc], kf, e[kk]);
      }
    }

    // ---- online softmax (row max over 16 lanes of the column group)
    float alpha[4];
#pragma unroll
    for (int rr = 0; rr < 4; ++rr) {
      float tm = fmaxf(fmaxf(e[0][rr], e[1][rr]), fmaxf(e[2][rr], e[3][rr]));
      tm = fmaxf(tm, __shfl_xor(tm, 1));
      tm = fmaxf(tm, __shfl_xor(tm, 2));
      tm = fmaxf(tm, __shfl_xor(tm, 4));
      tm = fmaxf(tm, __shfl_xor(tm, 8));
      const float mn = fmaxf(mrow[rr], tm);
      alpha[rr] = __builtin_amdgcn_exp2f((mrow[rr] - mn) * SCALE_LOG2E);
      mrow[rr] = mn;
    }
    float psum[4] = {0.f, 0.f, 0.f, 0.f};
#pragma unroll
    for (int kk = 0; kk < 4; ++kk) {
#pragma unroll
      for (int rr = 0; rr < 4; ++rr) {
        const float p = __builtin_amdgcn_exp2f((e[kk][rr] - mrow[rr]) * SCALE_LOG2E);
        psum[rr] += p;
        pls[wid][(lg * 4 + rr) * 72 + kk * 16 + lr] = (__bf16)p;  // wave-local
      }
    }
#pragma unroll
    for (int rr = 0; rr < 4; ++rr) {
      float ps = psum[rr];
      ps += __shfl_xor(ps, 1);
      ps += __shfl_xor(ps, 2);
      ps += __shfl_xor(ps, 4);
      ps += __shfl_xor(ps, 8);
      lrow[rr] = lrow[rr] * alpha[rr] + ps;
      o[0][rr] *= alpha[rr];
      o[1][rr] *= alpha[rr];
      o[2][rr] *= alpha[rr];
      o[3][rr] *= alpha[rr];
    }

    // ---- PV: A = P (from per-wave LDS re-layout), B = V^T tile
    asm volatile("s_waitcnt lgkmcnt(0)" ::: "memory");  // wave-local W->R fence
    bf16x8 pa[2];
    pa[0] = *(const bf16x8*)(&pls[wid][lr * 72 + lg * 8]);
    pa[1] = *(const bf16x8*)(&pls[wid][lr * 72 + 32 + lg * 8]);
#pragma unroll
    for (int db = 0; db < 4; ++db) {
#pragma unroll
      for (int kc = 0; kc < 2; ++kc) {
        const int row = db * 16 + lr;
        bf16x8 vf = *(const bf16x8*)(&vls[row * 64 + (((kc * 4 + lg) ^ (row & 7)) * 8)]);
        o[db] = mfma16(pa[kc], vf, o[db]);
      }
    }
    __syncthreads();  // all reads done before next tile's staging
  }

  // ---- epilogue: normalize, project with Wo, add bo, store f32 [b,s,h,e]
#pragma unroll
  for (int rr = 0; rr < 4; ++rr) {
    const float inv = __builtin_amdgcn_rcpf(lrow[rr]);
#pragma unroll
    for (int db = 0; db < 4; ++db)
      pls[wid][(lg * 4 + rr) * 72 + db * 16 + lr] = (__bf16)(o[db][rr] * inv);
  }
  asm volatile("s_waitcnt lgkmcnt(0)" ::: "memory");
  bf16x8 of0 = *(const bf16x8*)(&pls[wid][lr * 72 + lg * 8]);
  bf16x8 of1 = *(const bf16x8*)(&pls[wid][lr * 72 + 32 + lg * 8]);
#pragma unroll
  for (int cb = 0; cb < 4; ++cb) {
    bf16x8 w0 = cvt8(Wo + (cb * 16 + lr) * Dc + lg * 8);
    bf16x8 w1 = cvt8(Wo + (cb * 16 + lr) * Dc + 32 + lg * 8);
    f32x4 acc = zero4();
    acc = mfma16(of0, w0, acc);
    acc = mfma16(of1, w1, acc);
    const float bb = bo[cb * 16 + lr];
#pragma unroll
    for (int rr = 0; rr < 4; ++rr) {
      const int s = q0 + wid * 16 + lg * 4 + rr;
      out[(((size_t)b * Sc + s) * Hc + h) * Dc + cb * 16 + lr] = acc[rr] + bb;
    }
  }
}

extern "C" void kernel_launch(void* const* d_in, const int* in_sizes, int n_in,
                              void* d_out, int out_size, void* d_ws, size_t ws_size,
                              hipStream_t stream) {
  const float* x  = (const float*)d_in[0];
  const float* Wq = (const float*)d_in[1];
  const float* bq = (const float*)d_in[2];
  const float* Wk = (const float*)d_in[3];
  const float* bk = (const float*)d_in[4];
  const float* Wv = (const float*)d_in[5];
  const float* bv = (const float*)d_in[6];
  const float* Wo = (const float*)d_in[7];
  const float* bo = (const float*)d_in[8];
  float* outp = (float*)d_out;

  const size_t elems = (size_t)Bc * Hc * Sc * Dc;  // 8.39M
  __bf16* Qw = (__bf16*)d_ws;
  __bf16* Kw = Qw + elems;
  __bf16* Vw = Kw + elems;   // total 48 MB of d_ws

  qkv_kernel<<<dim3((Bc * Sc * Hc) / 256), dim3(256), 0, stream>>>(
      x, Wq, bq, Wk, bk, Wv, bv, Qw, Kw, Vw);
  attn_kernel<<<dim3(Bc * Hc * (Sc / 64)), dim3(256), 0, stream>>>(
      Qw, Kw, Vw, Wo, bo, outp);
}

// Round 5
// 243.288 us; speedup vs baseline: 1.4344x; 1.4344x over previous
//
#include <hip/hip_runtime.h>
#include <hip/hip_bf16.h>

#define Bc 8
#define Sc 2048
#define Hc 8
#define Dc 64

// softmax scale folded into Q at projection time: (1/sqrt(64)) * log2(e)
#define SCALE_LOG2E 0.18033688011112042f

typedef __bf16 bf16x8 __attribute__((ext_vector_type(8)));
typedef __bf16 bf16x4 __attribute__((ext_vector_type(4)));
typedef float f32x4 __attribute__((ext_vector_type(4)));

__device__ __forceinline__ f32x4 mfma16(bf16x8 a, bf16x8 b, f32x4 c) {
  return __builtin_amdgcn_mfma_f32_16x16x32_bf16(a, b, c, 0, 0, 0);
}

__device__ __forceinline__ bf16x8 cvt8(const float* __restrict__ p) {
  bf16x8 r;
#pragma unroll
  for (int i = 0; i < 8; ++i) r[i] = (__bf16)p[i];
  return r;
}

__device__ __forceinline__ f32x4 zero4() {
  f32x4 z = {0.f, 0.f, 0.f, 0.f};
  return z;
}

typedef __attribute__((address_space(1))) void as1_void;
typedef __attribute__((address_space(3))) void as3_void;

// async global->LDS, 16B per lane; LDS dest is wave-uniform base + lane*16
__device__ __forceinline__ void lds_load16(const void* gsrc, void* ldst) {
  __builtin_amdgcn_global_load_lds((as1_void*)(void*)gsrc, (as3_void*)ldst, 16, 0, 0);
}

// ---------------------------------------------------------------------------
// Kernel 1: fused QKV projection, one (b,h) per block slice.
// Grid 512 = b(8) x h(8) x st(8); each block: 256 s-rows (4 iters x 64).
// All stores are s-contiguous (32B segments per 16 lanes) — no head interleave.
// Q is pre-scaled by SCALE_LOG2E.  Outputs: Qb/Kb [bh][s][d], Vt [bh][d][s].
// ---------------------------------------------------------------------------
__global__ __launch_bounds__(256) void qkv_kernel(
    const float* __restrict__ x,
    const float* __restrict__ Wq, const float* __restrict__ bq,
    const float* __restrict__ Wk, const float* __restrict__ bk,
    const float* __restrict__ Wv, const float* __restrict__ bv,
    __bf16* __restrict__ Qb, __bf16* __restrict__ Kb, __bf16* __restrict__ Vt)
{
  const int tid = threadIdx.x;
  const int wid = tid >> 6;
  const int lane = tid & 63;
  const int lr = lane & 15;
  const int lg = lane >> 4;

  const int bid = blockIdx.x;
  const int st = bid & 7;
  const int h  = (bid >> 3) & 7;
  const int b  = bid >> 6;
  const int bh = b * Hc + h;

  // Weight fragments: frag(W)[cb][dc] = W[(cb*16+lr)][dc*32 + lg*8 .. +8]
  bf16x8 wqf[4][2], wkf[4][2], wvf[4][2];
#pragma unroll
  for (int cb = 0; cb < 4; ++cb)
#pragma unroll
    for (int dc = 0; dc < 2; ++dc) {
      const int off = (cb * 16 + lr) * Dc + dc * 32 + lg * 8;
      wqf[cb][dc] = cvt8(Wq + off);
      wkf[cb][dc] = cvt8(Wk + off);
      wvf[cb][dc] = cvt8(Wv + off);
    }
  float bqv[4], bkv[4], bvv[4][4];
#pragma unroll
  for (int cb = 0; cb < 4; ++cb) {
    bqv[cb] = bq[cb * 16 + lr];
    bkv[cb] = bk[cb * 16 + lr];
  }
#pragma unroll
  for (int eb = 0; eb < 4; ++eb)
#pragma unroll
    for (int rr = 0; rr < 4; ++rr) bvv[eb][rr] = bv[eb * 16 + lg * 4 + rr];

#pragma unroll 1
  for (int it = 0; it < 4; ++it) {
    const int s0 = st * 256 + it * 64 + wid * 16;  // this wave's 16 rows
    bf16x8 xf[2];
#pragma unroll
    for (int dc = 0; dc < 2; ++dc)
      xf[dc] = cvt8(x + ((size_t)(b * Sc + s0 + lr) * Hc + h) * Dc + dc * 32 + lg * 8);

    // Q (scaled) and K: C row = s-row (lg*4+rr), col = e (cb*16+lr)
#pragma unroll
    for (int cb = 0; cb < 4; ++cb) {
      f32x4 aq = zero4(), ak = zero4();
      aq = mfma16(xf[0], wqf[cb][0], aq);
      aq = mfma16(xf[1], wqf[cb][1], aq);
      ak = mfma16(xf[0], wkf[cb][0], ak);
      ak = mfma16(xf[1], wkf[cb][1], ak);
#pragma unroll
      for (int rr = 0; rr < 4; ++rr) {
        const size_t row = (size_t)bh * Sc + s0 + lg * 4 + rr;
        Qb[row * Dc + cb * 16 + lr] = (__bf16)((aq[rr] + bqv[cb]) * SCALE_LOG2E);
        Kb[row * Dc + cb * 16 + lr] = (__bf16)(ak[rr] + bkv[cb]);
      }
    }
    // V swapped: C row = e (eb*16+lg*4+rr), col = s-row (lr) -> s-contiguous
#pragma unroll
    for (int eb = 0; eb < 4; ++eb) {
      f32x4 av = zero4();
      av = mfma16(wvf[eb][0], xf[0], av);
      av = mfma16(wvf[eb][1], xf[1], av);
#pragma unroll
      for (int rr = 0; rr < 4; ++rr) {
        const int e = eb * 16 + lg * 4 + rr;
        Vt[((size_t)bh * Dc + e) * Sc + s0 + lr] = (__bf16)(av[rr] + bvv[eb][rr]);
      }
    }
  }
}

// ---------------------------------------------------------------------------
// Kernel 2: flash attention + fused output projection.
// Block = 256 thr (4 waves). QBLK=128 (32 q-rows/wave in 2 subtiles), KBLK=64.
// Double-buffered K/V staging with counted vmcnt(4) — loads stay in flight
// across raw s_barriers (T3/T4-lite).  Swapped QK^T (mfma(K,Q)) puts a full
// 16-value P-slice per lane -> in-lane max/sum + 2 shuffles; P repacked to
// LDS with 4x ds_write_b64.  Defer-max rescale (THR=8).
// ---------------------------------------------------------------------------
__global__ __launch_bounds__(256) void attn_kernel(
    const __bf16* __restrict__ Qb, const __bf16* __restrict__ Kb,
    const __bf16* __restrict__ Vt, const float* __restrict__ Wo,
    const float* __restrict__ bo, float* __restrict__ out)
{
  __shared__ __align__(16) __bf16 kls[2][64 * 64];
  __shared__ __align__(16) __bf16 vls[2][64 * 64];
  __shared__ __align__(16) __bf16 pls[4][2][16 * 72];

  const int tid = threadIdx.x;
  const int wid = tid >> 6;
  const int lane = tid & 63;
  const int lr = lane & 15;
  const int lg = lane >> 4;

  // bh = bid & 63: all 16 q-blocks of one bh keep a stable XCD (bid % 8)
  const int bid = blockIdx.x;
  const int bh = bid & 63;
  const int qb = bid >> 6;
  const int b = bh >> 3, h = bh & 7;
  const int q0 = qb * 128 + wid * 32;

  const __bf16* Kbase = Kb + (size_t)bh * Sc * Dc;
  const __bf16* Vbase = Vt + (size_t)bh * Dc * Sc;

  // Q fragments (B-operand of swapped QK^T): qf[sub][dc]
  bf16x8 qf[2][2];
#pragma unroll
  for (int sub = 0; sub < 2; ++sub)
#pragma unroll
    for (int dc = 0; dc < 2; ++dc)
      qf[sub][dc] = *(const bf16x8*)(Qb +
          ((size_t)bh * Sc + q0 + sub * 16 + lr) * Dc + dc * 32 + lg * 8);

  f32x4 o[2][4];
#pragma unroll
  for (int sub = 0; sub < 2; ++sub)
#pragma unroll
    for (int db = 0; db < 4; ++db) o[sub][db] = zero4();
  float mrow[2] = {-1e30f, -1e30f}, lrow[2] = {0.f, 0.f};

  // prologue: stage tile 0 into buffer 0 (4 gload_lds per wave)
  {
#pragma unroll
    for (int i = 0; i < 2; ++i) {
      const int s = i * 256 + tid, r = s >> 3, c = s & 7;
      lds_load16(Kbase + (size_t)r * Dc + ((c ^ (r & 7)) * 8),
                 &kls[0][(i * 256 + wid * 64) * 8]);
    }
#pragma unroll
    for (int i = 0; i < 2; ++i) {
      const int s = i * 256 + tid, d = s >> 3, c = s & 7;
      lds_load16(Vbase + (size_t)d * Sc + ((c ^ (d & 7)) * 8),
                 &vls[0][(i * 256 + wid * 64) * 8]);
    }
  }

#pragma unroll 1
  for (int kt = 0; kt < Sc / 64; ++kt) {
    const int cur = kt & 1;
    const int nk0 = ((kt + 1) & 31) * 64;
    // ---- issue next tile's staging into buf^1 (stays in flight past barrier)
    __builtin_amdgcn_sched_barrier(0);
#pragma unroll
    for (int i = 0; i < 2; ++i) {
      const int s = i * 256 + tid, r = s >> 3, c = s & 7;
      lds_load16(Kbase + (size_t)(nk0 + r) * Dc + ((c ^ (r & 7)) * 8),
                 &kls[cur ^ 1][(i * 256 + wid * 64) * 8]);
    }
#pragma unroll
    for (int i = 0; i < 2; ++i) {
      const int s = i * 256 + tid, d = s >> 3, c = s & 7;
      lds_load16(Vbase + (size_t)d * Sc + nk0 + ((c ^ (d & 7)) * 8),
                 &vls[cur ^ 1][(i * 256 + wid * 64) * 8]);
    }
    asm volatile("s_waitcnt vmcnt(4)" ::: "memory");  // this tile's 4 done
    __builtin_amdgcn_sched_barrier(0);
    __builtin_amdgcn_s_barrier();
    __builtin_amdgcn_sched_barrier(0);

    // ---- QK^T (swapped): e[sub][kk] -> lane holds S[k=kk*16+lg*4+rr][q=lr]
    f32x4 e[2][4];
#pragma unroll
    for (int sub = 0; sub < 2; ++sub)
#pragma unroll
      for (int kk = 0; kk < 4; ++kk) e[sub][kk] = zero4();
    __builtin_amdgcn_s_setprio(1);
#pragma unroll
    for (int kk = 0; kk < 4; ++kk) {
      const int row = kk * 16 + lr;
      bf16x8 kf0 = *(const bf16x8*)(&kls[cur][row * 64 + ((lg ^ (row & 7)) * 8)]);
      bf16x8 kf1 = *(const bf16x8*)(&kls[cur][row * 64 + (((4 + lg) ^ (row & 7)) * 8)]);
#pragma unroll
      for (int sub = 0; sub < 2; ++sub) {
        e[sub][kk] = mfma16(kf0, qf[sub][0], e[sub][kk]);
        e[sub][kk] = mfma16(kf1, qf[sub][1], e[sub][kk]);
      }
    }
    __builtin_amdgcn_s_setprio(0);

    // previous tile's pa reads are long consumed; safe to overwrite pls
    asm volatile("s_waitcnt lgkmcnt(0)" ::: "memory");
    __builtin_amdgcn_sched_barrier(0);

    // ---- softmax per subtile (all in-lane; q = lr)
#pragma unroll
    for (int sub = 0; sub < 2; ++sub) {
      float tm = e[sub][0][0];
#pragma unroll
      for (int kk = 0; kk < 4; ++kk)
#pragma unroll
        for (int rr = 0; rr < 4; ++rr) tm = fmaxf(tm, e[sub][kk][rr]);
      tm = fmaxf(tm, __shfl_xor(tm, 16));
      tm = fmaxf(tm, __shfl_xor(tm, 32));
      if (!__all(tm - mrow[sub] <= 8.0f)) {   // defer-max: rescale rarely
        const float mn = fmaxf(mrow[sub], tm);
        const float al = __builtin_amdgcn_exp2f(mrow[sub] - mn);
#pragma unroll
        for (int db = 0; db < 4; ++db) {
          o[sub][db][0] *= al; o[sub][db][1] *= al;
          o[sub][db][2] *= al; o[sub][db][3] *= al;
        }
        lrow[sub] *= al;
        mrow[sub] = mn;
      }
      float ps = 0.f;
#pragma unroll
      for (int kk = 0; kk < 4; ++kk) {
        const float p0 = __builtin_amdgcn_exp2f(e[sub][kk][0] - mrow[sub]);
        const float p1 = __builtin_amdgcn_exp2f(e[sub][kk][1] - mrow[sub]);
        const float p2 = __builtin_amdgcn_exp2f(e[sub][kk][2] - mrow[sub]);
        const float p3 = __builtin_amdgcn_exp2f(e[sub][kk][3] - mrow[sub]);
        ps += (p0 + p1) + (p2 + p3);
        bf16x4 pk;
        pk[0] = (__bf16)p0; pk[1] = (__bf16)p1;
        pk[2] = (__bf16)p2; pk[3] = (__bf16)p3;
        *(bf16x4*)(&pls[wid][sub][lr * 72 + kk * 16 + lg * 4]) = pk;
      }
      ps += __shfl_xor(ps, 16);
      ps += __shfl_xor(ps, 32);
      lrow[sub] += ps;
    }
    asm volatile("s_waitcnt lgkmcnt(0)" ::: "memory");  // P writes visible
    __builtin_amdgcn_sched_barrier(0);

    // ---- PV: A = P (q=lr rows), B = V^T tile (d rows)
    bf16x8 pa[2][2];
#pragma unroll
    for (int sub = 0; sub < 2; ++sub)
#pragma unroll
      for (int kc = 0; kc < 2; ++kc)
        pa[sub][kc] = *(const bf16x8*)(&pls[wid][sub][lr * 72 + kc * 32 + lg * 8]);
    __builtin_amdgcn_s_setprio(1);
#pragma unroll
    for (int db = 0; db < 4; ++db) {
      const int row = db * 16 + lr;
      bf16x8 vf0 = *(const bf16x8*)(&vls[cur][row * 64 + ((lg ^ (row & 7)) * 8)]);
      bf16x8 vf1 = *(const bf16x8*)(&vls[cur][row * 64 + (((4 + lg) ^ (row & 7)) * 8)]);
#pragma unroll
      for (int sub = 0; sub < 2; ++sub) {
        o[sub][db] = mfma16(pa[sub][0], vf0, o[sub][db]);
        o[sub][db] = mfma16(pa[sub][1], vf1, o[sub][db]);
      }
    }
    __builtin_amdgcn_s_setprio(0);

    // all LDS reads of buf[cur] done before next iter overwrites it
    asm volatile("s_waitcnt lgkmcnt(0)" ::: "memory");
    __builtin_amdgcn_sched_barrier(0);
    __builtin_amdgcn_s_barrier();
  }

  // ---- epilogue: normalize, project with Wo, add bo, store f32 [b,s,h,e]
  bf16x8 wof[4][2];
#pragma unroll
  for (int cb = 0; cb < 4; ++cb)
#pragma unroll
    for (int dc = 0; dc < 2; ++dc)
      wof[cb][dc] = cvt8(Wo + (cb * 16 + lr) * Dc + dc * 32 + lg * 8);
  float bov[4];
#pragma unroll
  for (int cb = 0; cb < 4; ++cb) bov[cb] = bo[cb * 16 + lr];

#pragma unroll
  for (int sub = 0; sub < 2; ++sub) {
    const float linv = __builtin_amdgcn_rcpf(lrow[sub]);
    float lis[4];
#pragma unroll
    for (int rr = 0; rr < 4; ++rr) lis[rr] = __shfl(linv, lg * 4 + rr);
    asm volatile("s_waitcnt lgkmcnt(0)" ::: "memory");
    __builtin_amdgcn_sched_barrier(0);
#pragma unroll
    for (int db = 0; db < 4; ++db)
#pragma unroll
      for (int rr = 0; rr < 4; ++rr)
        pls[wid][sub][(lg * 4 + rr) * 72 + db * 16 + lr] =
            (__bf16)(o[sub][db][rr] * lis[rr]);
    asm volatile("s_waitcnt lgkmcnt(0)" ::: "memory");
    __builtin_amdgcn_sched_barrier(0);
    bf16x8 of0 = *(const bf16x8*)(&pls[wid][sub][lr * 72 + lg * 8]);
    bf16x8 of1 = *(const bf16x8*)(&pls[wid][sub][lr * 72 + 32 + lg * 8]);
#pragma unroll
    for (int cb = 0; cb < 4; ++cb) {
      f32x4 acc = zero4();
      acc = mfma16(of0, wof[cb][0], acc);
      acc = mfma16(of1, wof[cb][1], acc);
#pragma unroll
      for (int rr = 0; rr < 4; ++rr) {
        const int s = q0 + sub * 16 + lg * 4 + rr;
        out[(((size_t)b * Sc + s) * Hc + h) * Dc + cb * 16 + lr] = acc[rr] + bov[cb];
      }
    }
  }
}

extern "C" void kernel_launch(void* const* d_in, const int* in_sizes, int n_in,
                              void* d_out, int out_size, void* d_ws, size_t ws_size,
                              hipStream_t stream) {
  const float* x  = (const float*)d_in[0];
  const float* Wq = (const float*)d_in[1];
  const float* bq = (const float*)d_in[2];
  const float* Wk = (const float*)d_in[3];
  const float* bk = (const float*)d_in[4];
  const float* Wv = (const float*)d_in[5];
  const float* bv = (const float*)d_in[6];
  const float* Wo = (const float*)d_in[7];
  const float* bo = (const float*)d_in[8];
  float* outp = (float*)d_out;

  const size_t elems = (size_t)Bc * Hc * Sc * Dc;  // 8.39M
  __bf16* Qw = (__bf16*)d_ws;
  __bf16* Kw = Qw + elems;
  __bf16* Vw = Kw + elems;   // 48 MB of d_ws total

  qkv_kernel<<<dim3(Bc * Hc * 8), dim3(256), 0, stream>>>(
      x, Wq, bq, Wk, bk, Wv, bv, Qw, Kw, Vw);
  attn_kernel<<<dim3(Bc * Hc * (Sc / 128)), dim3(256), 0, stream>>>(
      Qw, Kw, Vw, Wo, bo, outp);
}